// Round 3
// baseline (226.162 us; speedup 1.0000x reference)
//
#include <hip/hip_runtime.h>
#include <hip/hip_bf16.h>
#include <cstdint>

// EdgeMLP: score = W3 @ sig(W2 @ sig(W1 @ [h1_u,h1_v,h2_u,h2_u] + b1) + b2) + b3
// Factored: z1 = Anode[src] + Bnode[dst]  (A/B stored bf16, PERMUTED col order:
//   dword slot d of a row holds true cols (32*(d>>4) + (d&15), +16) as (lo,hi);
//   the permutation is compensated in W2F's k-index in prep).
// Node layer: bf16 MFMA, weight frags register-resident per wave n-quarter.
// Edge layer 2: bf16 MFMA, register B-frags.
// R10: edge_kernel was latency-bound at 29% occupancy (VALU 47 / MFMA 9 / HBM 20
//   — no pipe saturated). LDS 36.9KB (hlds double-buffer) capped 4 blocks/CU.
//   Switch to SINGLE hlds buffer + TWO barriers per tile -> LDS 19.5KB ->
//   8 blocks/CU (100% occupancy cap). Grid 2048, __launch_bounds__(256,8).
//   Arithmetic bit-identical to R9 (packbf_rhu; no cvt_pk asm — R8 errata).

typedef __attribute__((ext_vector_type(8))) short bf16x8;
typedef __attribute__((ext_vector_type(4))) float f32x4;

__device__ __forceinline__ float sigmoid_fast(float x) {
    float e = __expf(-x);                       // v_mul + v_exp
    return __builtin_amdgcn_rcpf(1.0f + e);     // v_add + v_rcp  (~1 ulp)
}
__device__ __forceinline__ ushort f2bf_rne(float f) {      // prep path only
    uint32_t u = __float_as_uint(f);
    return (ushort)((u + 0x7fffu + ((u >> 16) & 1u)) >> 16);
}
__device__ __forceinline__ float bf2f_lo(uint32_t d) { return __uint_as_float(d << 16); }
__device__ __forceinline__ float bf2f_hi(uint32_t d) { return __uint_as_float(d & 0xffff0000u); }
__device__ __forceinline__ uint32_t packbf_rhu(float x, float y) {   // round-half-up
    return ((__float_as_uint(x) + 0x8000u) >> 16) |
           ((__float_as_uint(y) + 0x8000u) & 0xffff0000u);
}

// ---------- prep: weights -> bf16 MFMA B-fragment layouts ----------
// frag idx: ((kk*8+nt)*64+lane)*8 + j ; n = nt*16+(lane&15) ; kpos = kk*32+(lane>>4)*8+j
// WCF/WBF use true k = kpos. W2F uses permuted ktrue to match A/B dword packing.
__global__ void prep_kernel(const float* __restrict__ W1, const float* __restrict__ W2,
                            ushort* __restrict__ WCF, ushort* __restrict__ WBF,
                            ushort* __restrict__ W2F) {
    int i = blockIdx.x * blockDim.x + threadIdx.x;
    if (i >= 16384) return;
    int j = i & 7, lf = (i >> 3) & 63, nt = (i >> 9) & 7, kk = i >> 12;
    int n = nt * 16 + (lf & 15);
    int kpos = kk * 32 + ((lf >> 4) << 3) + j;
    int ktrue = (kpos & ~31) | ((kpos >> 1) & 15) | ((kpos & 1) << 4);
    W2F[i] = f2bf_rne(W2[n * 128 + ktrue]);
    float v = (kpos < 64) ? W1[n * 256 + kpos]
                          : W1[n * 256 + 128 + (kpos - 64)] + W1[n * 256 + 192 + (kpos - 64)];
    WCF[i] = f2bf_rne(v);
    if (kk < 2) WBF[i] = f2bf_rne(W1[n * 256 + 64 + kpos]);   // K=64: h1-half only
}

// ---------- node-side: MFMA, register weight frags, direct coalesced stores ----------
__global__ __launch_bounds__(256, 4) void node_kernel(
    const float* __restrict__ h1, const float* __restrict__ h2,
    const ushort* __restrict__ WCF, const ushort* __restrict__ WBF,
    const float* __restrict__ b1,
    uint32_t* __restrict__ Aout, uint32_t* __restrict__ Bout, int N)
{
    __shared__ __align__(16) ushort xt[64 * 136];   // [node][k true order]
    const int tid = threadIdx.x, g = tid >> 6, ln = tid & 63;
    const int nl = ln & 15, q = ln >> 4;
    const int n0 = blockIdx.x * 64;
    const bool full = (n0 + 64 <= N);

    // wave g owns n-cols [g*32, g*32+32): 12 weight frags -> 48 VGPRs
    bf16x8 fa[4][2], fb[2][2];
    #pragma unroll
    for (int kk = 0; kk < 4; ++kk)
        #pragma unroll
        for (int nt = 0; nt < 2; ++nt)
            fa[kk][nt] = *(const bf16x8*)(WCF + (((kk * 8 + g * 2 + nt) * 64 + ln) << 3));
    #pragma unroll
    for (int kk = 0; kk < 2; ++kk)
        #pragma unroll
        for (int nt = 0; nt < 2; ++nt)
            fb[kk][nt] = *(const bf16x8*)(WBF + (((kk * 8 + g * 2 + nt) * 64 + ln) << 3));
    const float b1c0 = b1[g * 32 + nl], b1c1 = b1[g * 32 + 16 + nl];

    // stage X = [h1|h2] as bf16 (true k order)
    #pragma unroll
    for (int i = 0; i < 8; ++i) {
        int local = i * 256 + tid;
        int node = local >> 5;
        int kq = (local & 31) * 4;
        float4 x = make_float4(0.f, 0.f, 0.f, 0.f);
        if (full || n0 + node < N)
            x = (kq < 64) ? *(const float4*)(h1 + (size_t)(n0 + node) * 64 + kq)
                          : *(const float4*)(h2 + (size_t)(n0 + node) * 64 + (kq - 64));
        uint32_t d0 = packbf_rhu(x.x, x.y), d1 = packbf_rhu(x.z, x.w);
        *(uint2*)&xt[node * 136 + kq] = make_uint2(d0, d1);
    }
    __syncthreads();

    #pragma unroll
    for (int m = 0; m < 4; ++m) {
        f32x4 accA[2], accB[2];
        #pragma unroll
        for (int r = 0; r < 4; ++r) { accA[0][r] = accA[1][r] = accB[0][r] = accB[1][r] = 0.f; }
        const ushort* arow = &xt[(m * 16 + nl) * 136 + (q << 3)];
        #pragma unroll
        for (int kk = 0; kk < 4; ++kk) {
            bf16x8 a = *(const bf16x8*)(arow + kk * 32);
            accA[0] = __builtin_amdgcn_mfma_f32_16x16x32_bf16(a, fa[kk][0], accA[0], 0, 0, 0);
            accA[1] = __builtin_amdgcn_mfma_f32_16x16x32_bf16(a, fa[kk][1], accA[1], 0, 0, 0);
            if (kk < 2) {
                accB[0] = __builtin_amdgcn_mfma_f32_16x16x32_bf16(a, fb[kk][0], accB[0], 0, 0, 0);
                accB[1] = __builtin_amdgcn_mfma_f32_16x16x32_bf16(a, fb[kk][1], accB[1], 0, 0, 0);
            }
        }
        // C/D: node = m*16 + q*4 + r, cols (g*32+nl, +16) -> dword slot g*16+nl
        #pragma unroll
        for (int r = 0; r < 4; ++r) {
            int node = n0 + m * 16 + q * 4 + r;
            if (full || node < N) {
                Aout[(size_t)node * 64 + g * 16 + nl] = packbf_rhu(accA[0][r] + b1c0, accA[1][r] + b1c1);
                Bout[(size_t)node * 64 + g * 16 + nl] = packbf_rhu(accB[0][r], accB[1][r]);
            }
        }
    }
}

// ---------- edge-side: gather + sigmoid + MFMA layer2 + fused layer3 ----------
// Single hlds buffer, two barriers per tile:
//   commit gathers(t) -> hlds           (bar2 of prev iter guarantees hlds free)
//   issue idx loads t+2G ; issue gathers t+G
//   bar1: hlds ready; part[buf^1] (prev tile) complete
//   out-write(prev) from part[buf^1] ; MFMA(t) reads hlds -> part[buf]
//   bar2: hlds consumed (next commit may overwrite)
__global__ __launch_bounds__(256, 8) void edge_kernel(
    const uint32_t* __restrict__ Am, const uint32_t* __restrict__ Bm,
    const int* __restrict__ src, const int* __restrict__ dst,
    const ushort* __restrict__ W2F, const float* __restrict__ b2,
    const float* __restrict__ W3, const float* __restrict__ b3,
    float* __restrict__ out, int E, int ntiles)
{
    __shared__ __align__(16) ushort hlds[64 * 136];   // 17408 B (single buffer)
    __shared__ float part[2][256];                    // 2048 B
    const int tid = threadIdx.x, g = tid >> 6, ln = tid & 63;
    const int nl = ln & 15, q = ln >> 4;
    const int el = g * 16 + (ln >> 2);   // gather: edge-local for this lane's quad
    const int p  = ln & 3;               // gather: 16B-quad within row
    const int G  = gridDim.x;

    // register B-frags: this wave's n-quarter (cols g*32..+31), K=128
    bf16x8 bfrag[8];
    #pragma unroll
    for (int kk = 0; kk < 4; ++kk)
        #pragma unroll
        for (int nt = 0; nt < 2; ++nt)
            bfrag[kk * 2 + nt] =
                *(const bf16x8*)(W2F + (((kk * 8 + g * 2 + nt) * 64 + ln) << 3));
    float b2c[2], w3c[2];
    #pragma unroll
    for (int nt = 0; nt < 2; ++nt) {
        int n = g * 32 + nt * 16 + nl;
        b2c[nt] = b2[n]; w3c[nt] = W3[n];
    }
    const float b3c = b3[0];

    uint4 ga[4], gb[4];
    int uB = 0, vB = 0;                  // indices for tile t+G (gathered next iter)
    int t = blockIdx.x;
    if (t < ntiles) {
        // prologue: indices + gather for tile t (per-lane direct, quad-broadcast)
        int e0 = t * 64 + el;
        int u0 = 0, v0 = 0;
        if (e0 < E) { u0 = src[e0]; v0 = dst[e0]; }
        const uint32_t* ap = Am + (size_t)u0 * 64 + p * 4;
        const uint32_t* bp = Bm + (size_t)v0 * 64 + p * 4;
        #pragma unroll
        for (int r = 0; r < 4; ++r) {
            ga[r] = *(const uint4*)(ap + r * 16);
            gb[r] = *(const uint4*)(bp + r * 16);
        }
        int t1 = t + G;                  // prologue idx-prefetch for t+G
        if (t1 < ntiles) {
            int e1 = t1 * 64 + el;
            if (e1 < E) { uB = src[e1]; vB = dst[e1]; }
        }
    }
    int buf = 0, prev = -1;
    for (; t < ntiles; t += G) {
        // ---- commit gather: sigmoid + pack -> hlds ----
        #pragma unroll
        for (int r = 0; r < 4; ++r) {
            uint32_t sa[4] = {ga[r].x, ga[r].y, ga[r].z, ga[r].w};
            uint32_t sb[4] = {gb[r].x, gb[r].y, gb[r].z, gb[r].w};
            uint32_t da[4];
            #pragma unroll
            for (int d = 0; d < 4; ++d) {
                float zl = bf2f_lo(sa[d]) + bf2f_lo(sb[d]);
                float zh = bf2f_hi(sa[d]) + bf2f_hi(sb[d]);
                da[d] = packbf_rhu(sigmoid_fast(zl), sigmoid_fast(zh));
            }
            *(uint4*)&hlds[el * 136 + r * 32 + p * 8] =
                make_uint4(da[0], da[1], da[2], da[3]);
        }
        // ---- issue idx loads for t+2G (consumed two iterations from now) ----
        int uC = 0, vC = 0;
        int t2 = t + 2 * G;
        if (t2 < ntiles) {
            int e2 = t2 * 64 + el;
            if (e2 < E) { uC = src[e2]; vC = dst[e2]; }
        }
        // ---- issue gathers for t+G (indices resident since last iteration) ----
        if (t + G < ntiles) {
            const uint32_t* ap = Am + (size_t)uB * 64 + p * 4;
            const uint32_t* bp = Bm + (size_t)vB * 64 + p * 4;
            #pragma unroll
            for (int r = 0; r < 4; ++r) {
                ga[r] = *(const uint4*)(ap + r * 16);
                gb[r] = *(const uint4*)(bp + r * 16);
            }
        }
        __syncthreads();   // bar1: hlds ready; part[buf^1] (prev tile) complete

        // ---- delayed out-write for previous tile ----
        if (prev >= 0 && tid < 64) {
            int e = prev * 64 + tid;
            if (e < E)
                out[e] = (part[buf ^ 1][tid] + part[buf ^ 1][64 + tid])
                       + (part[buf ^ 1][128 + tid] + part[buf ^ 1][192 + tid]) + b3c;
        }

        // ---- MFMA + epilogue -> part[buf] ----
        #pragma unroll
        for (int m = 0; m < 4; ++m) {
            f32x4 acc[2];
            #pragma unroll
            for (int r = 0; r < 4; ++r) { acc[0][r] = 0.f; acc[1][r] = 0.f; }
            const ushort* arow = &hlds[(m * 16 + nl) * 136 + (q << 3)];
            #pragma unroll
            for (int kk = 0; kk < 4; ++kk) {
                bf16x8 a = *(const bf16x8*)(arow + kk * 32);
                acc[0] = __builtin_amdgcn_mfma_f32_16x16x32_bf16(a, bfrag[kk * 2],     acc[0], 0, 0, 0);
                acc[1] = __builtin_amdgcn_mfma_f32_16x16x32_bf16(a, bfrag[kk * 2 + 1], acc[1], 0, 0, 0);
            }
            float pr[4] = {0.f, 0.f, 0.f, 0.f};
            #pragma unroll
            for (int nt = 0; nt < 2; ++nt)
                #pragma unroll
                for (int r = 0; r < 4; ++r)
                    pr[r] = fmaf(w3c[nt], sigmoid_fast(acc[nt][r] + b2c[nt]), pr[r]);
            #pragma unroll
            for (int r = 0; r < 4; ++r) {
                pr[r] += __shfl_xor(pr[r], 1, 16);
                pr[r] += __shfl_xor(pr[r], 2, 16);
                pr[r] += __shfl_xor(pr[r], 4, 16);
                pr[r] += __shfl_xor(pr[r], 8, 16);
            }
            if (nl == 0) {
                #pragma unroll
                for (int r = 0; r < 4; ++r)
                    part[buf][g * 64 + m * 16 + q * 4 + r] = pr[r];
            }
        }
        __syncthreads();   // bar2: hlds consumed; part[buf] complete
        uB = uC; vB = vC;
        prev = t; buf ^= 1;
    }
    // ---- drain: out-write for the final tile (bar2 already synced part) ----
    if (prev >= 0 && tid < 64) {
        int e = prev * 64 + tid;
        if (e < E)
            out[e] = (part[buf ^ 1][tid] + part[buf ^ 1][64 + tid])
                   + (part[buf ^ 1][128 + tid] + part[buf ^ 1][192 + tid]) + b3c;
    }
}

// ---------- fallback (only if workspace too small) ----------
__global__ void naive_kernel(
    const float* __restrict__ h1, const float* __restrict__ h2,
    const int* __restrict__ src, const int* __restrict__ dst,
    const float* __restrict__ W1, const float* __restrict__ b1,
    const float* __restrict__ W2, const float* __restrict__ b2,
    const float* __restrict__ W3, const float* __restrict__ b3,
    float* __restrict__ out, int E, int N)
{
    int e = blockIdx.x * blockDim.x + threadIdx.x;
    if (e >= E) return;
    int u = src[e], v = dst[e];
    float h[128];
    for (int j = 0; j < 128; ++j) {
        float z = b1[j];
        const float* wj = W1 + j * 256;
        for (int k = 0; k < 64; ++k) {
            z += wj[k] * h1[(size_t)u * 64 + k]
               + wj[64 + k] * h1[(size_t)v * 64 + k]
               + (wj[128 + k] + wj[192 + k]) * h2[(size_t)u * 64 + k];
        }
        h[j] = 1.0f / (1.0f + __expf(-z));
    }
    float gg[128];
    for (int j = 0; j < 128; ++j) {
        float z = b2[j];
        for (int k = 0; k < 128; ++k) z = fmaf(W2[j * 128 + k], h[k], z);
        gg[j] = 1.0f / (1.0f + __expf(-z));
    }
    float s = b3[0];
    for (int j = 0; j < 128; ++j) s = fmaf(W3[j], gg[j], s);
    out[e] = s;
}

extern "C" void kernel_launch(void* const* d_in, const int* in_sizes, int n_in,
                              void* d_out, int out_size, void* d_ws, size_t ws_size,
                              hipStream_t stream) {
    const float* h1 = (const float*)d_in[0];
    const float* h2 = (const float*)d_in[1];
    const int*  src = (const int*)d_in[2];
    const int*  dst = (const int*)d_in[3];
    const float* W1 = (const float*)d_in[4];
    const float* b1 = (const float*)d_in[5];
    const float* W2 = (const float*)d_in[6];
    const float* b2 = (const float*)d_in[7];
    const float* W3 = (const float*)d_in[8];
    const float* b3 = (const float*)d_in[9];
    float* out = (float*)d_out;

    const int N = in_sizes[0] / 64;
    const int E = in_sizes[2];

    // workspace layout (float units)
    size_t offA   = 0;                         // N*64 dwords (bf16-pair packed)
    size_t offB   = offA + (size_t)N * 64;
    size_t offWCF = offB + (size_t)N * 64;     // 16384 ushorts
    size_t offWBF = offWCF + 8192;             // 8192 ushorts
    size_t offW2F = offWBF + 4096;             // 16384 ushorts
    size_t totalF = offW2F + 8192;

    if (ws_size < totalF * sizeof(float)) {
        naive_kernel<<<(E + 255) / 256, 256, 0, stream>>>(
            h1, h2, src, dst, W1, b1, W2, b2, W3, b3, out, E, N);
        return;
    }

    float* ws = (float*)d_ws;
    ushort* WCF = (ushort*)(ws + offWCF);
    ushort* WBF = (ushort*)(ws + offWBF);
    ushort* W2F = (ushort*)(ws + offW2F);

    prep_kernel<<<64, 256, 0, stream>>>(W1, W2, WCF, WBF, W2F);
    node_kernel<<<(N + 63) / 64, 256, 0, stream>>>(
        h1, h2, WCF, WBF, b1, (uint32_t*)(ws + offA), (uint32_t*)(ws + offB), N);
    const int ntiles = (E + 63) / 64;
    const int nblk = ntiles < 2048 ? ntiles : 2048;   // 8 blocks/CU resident (19.5KB LDS)
    edge_kernel<<<nblk, 256, 0, stream>>>(
        (const uint32_t*)(ws + offA), (const uint32_t*)(ws + offB), src, dst,
        W2F, b2, W3, b3, out, E, ntiles);
}

// Round 4
// 134.701 us; speedup vs baseline: 1.6790x; 1.6790x over previous
//
#include <hip/hip_runtime.h>
#include <hip/hip_bf16.h>
#include <cstdint>

// EdgeMLP: score = W3 @ sig(W2 @ sig(W1 @ [h1_u,h1_v,h2_u,h2_u] + b1) + b2) + b3
// Factored: z1 = Anode[src] + Bnode[dst]  (A/B stored bf16, PERMUTED col order:
//   dword slot d of a row holds true cols (32*(d>>4) + (d&15), +16) as (lo,hi);
//   the permutation is compensated in W2F's k-index in prep).
// Node layer: bf16 MFMA, weight frags register-resident per wave n-quarter.
// Edge layer 2: bf16 MFMA, register B-frags.
// R11: R10's __launch_bounds__(256,8) capped VGPRs at 32 -> massive scratch
//   spills (WRITE_SIZE 1.25->106 MB, FETCH +298 MB, 136 µs). Keep the
//   single-hlds-buffer/two-barrier structure (19.5KB LDS, 8 blocks/CU cap)
//   but restore (256,4): allocator lands ~56 VGPR (<=64), so HW can still
//   run 8 waves/SIMD. One variable changed vs R9.

typedef __attribute__((ext_vector_type(8))) short bf16x8;
typedef __attribute__((ext_vector_type(4))) float f32x4;

__device__ __forceinline__ float sigmoid_fast(float x) {
    float e = __expf(-x);                       // v_mul + v_exp
    return __builtin_amdgcn_rcpf(1.0f + e);     // v_add + v_rcp  (~1 ulp)
}
__device__ __forceinline__ ushort f2bf_rne(float f) {      // prep path only
    uint32_t u = __float_as_uint(f);
    return (ushort)((u + 0x7fffu + ((u >> 16) & 1u)) >> 16);
}
__device__ __forceinline__ float bf2f_lo(uint32_t d) { return __uint_as_float(d << 16); }
__device__ __forceinline__ float bf2f_hi(uint32_t d) { return __uint_as_float(d & 0xffff0000u); }
__device__ __forceinline__ uint32_t packbf_rhu(float x, float y) {   // round-half-up
    return ((__float_as_uint(x) + 0x8000u) >> 16) |
           ((__float_as_uint(y) + 0x8000u) & 0xffff0000u);
}

// ---------- prep: weights -> bf16 MFMA B-fragment layouts ----------
// frag idx: ((kk*8+nt)*64+lane)*8 + j ; n = nt*16+(lane&15) ; kpos = kk*32+(lane>>4)*8+j
// WCF/WBF use true k = kpos. W2F uses permuted ktrue to match A/B dword packing.
__global__ void prep_kernel(const float* __restrict__ W1, const float* __restrict__ W2,
                            ushort* __restrict__ WCF, ushort* __restrict__ WBF,
                            ushort* __restrict__ W2F) {
    int i = blockIdx.x * blockDim.x + threadIdx.x;
    if (i >= 16384) return;
    int j = i & 7, lf = (i >> 3) & 63, nt = (i >> 9) & 7, kk = i >> 12;
    int n = nt * 16 + (lf & 15);
    int kpos = kk * 32 + ((lf >> 4) << 3) + j;
    int ktrue = (kpos & ~31) | ((kpos >> 1) & 15) | ((kpos & 1) << 4);
    W2F[i] = f2bf_rne(W2[n * 128 + ktrue]);
    float v = (kpos < 64) ? W1[n * 256 + kpos]
                          : W1[n * 256 + 128 + (kpos - 64)] + W1[n * 256 + 192 + (kpos - 64)];
    WCF[i] = f2bf_rne(v);
    if (kk < 2) WBF[i] = f2bf_rne(W1[n * 256 + 64 + kpos]);   // K=64: h1-half only
}

// ---------- node-side: MFMA, register weight frags, direct coalesced stores ----------
__global__ __launch_bounds__(256, 4) void node_kernel(
    const float* __restrict__ h1, const float* __restrict__ h2,
    const ushort* __restrict__ WCF, const ushort* __restrict__ WBF,
    const float* __restrict__ b1,
    uint32_t* __restrict__ Aout, uint32_t* __restrict__ Bout, int N)
{
    __shared__ __align__(16) ushort xt[64 * 136];   // [node][k true order]
    const int tid = threadIdx.x, g = tid >> 6, ln = tid & 63;
    const int nl = ln & 15, q = ln >> 4;
    const int n0 = blockIdx.x * 64;
    const bool full = (n0 + 64 <= N);

    // wave g owns n-cols [g*32, g*32+32): 12 weight frags -> 48 VGPRs
    bf16x8 fa[4][2], fb[2][2];
    #pragma unroll
    for (int kk = 0; kk < 4; ++kk)
        #pragma unroll
        for (int nt = 0; nt < 2; ++nt)
            fa[kk][nt] = *(const bf16x8*)(WCF + (((kk * 8 + g * 2 + nt) * 64 + ln) << 3));
    #pragma unroll
    for (int kk = 0; kk < 2; ++kk)
        #pragma unroll
        for (int nt = 0; nt < 2; ++nt)
            fb[kk][nt] = *(const bf16x8*)(WBF + (((kk * 8 + g * 2 + nt) * 64 + ln) << 3));
    const float b1c0 = b1[g * 32 + nl], b1c1 = b1[g * 32 + 16 + nl];

    // stage X = [h1|h2] as bf16 (true k order)
    #pragma unroll
    for (int i = 0; i < 8; ++i) {
        int local = i * 256 + tid;
        int node = local >> 5;
        int kq = (local & 31) * 4;
        float4 x = make_float4(0.f, 0.f, 0.f, 0.f);
        if (full || n0 + node < N)
            x = (kq < 64) ? *(const float4*)(h1 + (size_t)(n0 + node) * 64 + kq)
                          : *(const float4*)(h2 + (size_t)(n0 + node) * 64 + (kq - 64));
        uint32_t d0 = packbf_rhu(x.x, x.y), d1 = packbf_rhu(x.z, x.w);
        *(uint2*)&xt[node * 136 + kq] = make_uint2(d0, d1);
    }
    __syncthreads();

    #pragma unroll
    for (int m = 0; m < 4; ++m) {
        f32x4 accA[2], accB[2];
        #pragma unroll
        for (int r = 0; r < 4; ++r) { accA[0][r] = accA[1][r] = accB[0][r] = accB[1][r] = 0.f; }
        const ushort* arow = &xt[(m * 16 + nl) * 136 + (q << 3)];
        #pragma unroll
        for (int kk = 0; kk < 4; ++kk) {
            bf16x8 a = *(const bf16x8*)(arow + kk * 32);
            accA[0] = __builtin_amdgcn_mfma_f32_16x16x32_bf16(a, fa[kk][0], accA[0], 0, 0, 0);
            accA[1] = __builtin_amdgcn_mfma_f32_16x16x32_bf16(a, fa[kk][1], accA[1], 0, 0, 0);
            if (kk < 2) {
                accB[0] = __builtin_amdgcn_mfma_f32_16x16x32_bf16(a, fb[kk][0], accB[0], 0, 0, 0);
                accB[1] = __builtin_amdgcn_mfma_f32_16x16x32_bf16(a, fb[kk][1], accB[1], 0, 0, 0);
            }
        }
        // C/D: node = m*16 + q*4 + r, cols (g*32+nl, +16) -> dword slot g*16+nl
        #pragma unroll
        for (int r = 0; r < 4; ++r) {
            int node = n0 + m * 16 + q * 4 + r;
            if (full || node < N) {
                Aout[(size_t)node * 64 + g * 16 + nl] = packbf_rhu(accA[0][r] + b1c0, accA[1][r] + b1c1);
                Bout[(size_t)node * 64 + g * 16 + nl] = packbf_rhu(accB[0][r], accB[1][r]);
            }
        }
    }
}

// ---------- edge-side: gather + sigmoid + MFMA layer2 + fused layer3 ----------
// Single hlds buffer, two barriers per tile:
//   commit gathers(t) -> hlds           (bar2 of prev iter guarantees hlds free)
//   issue idx loads t+2G ; issue gathers t+G
//   bar1: hlds ready; part[buf^1] (prev tile) complete
//   out-write(prev) from part[buf^1] ; MFMA(t) reads hlds -> part[buf]
//   bar2: hlds consumed (next commit may overwrite)
__global__ __launch_bounds__(256, 4) void edge_kernel(
    const uint32_t* __restrict__ Am, const uint32_t* __restrict__ Bm,
    const int* __restrict__ src, const int* __restrict__ dst,
    const ushort* __restrict__ W2F, const float* __restrict__ b2,
    const float* __restrict__ W3, const float* __restrict__ b3,
    float* __restrict__ out, int E, int ntiles)
{
    __shared__ __align__(16) ushort hlds[64 * 136];   // 17408 B (single buffer)
    __shared__ float part[2][256];                    // 2048 B
    const int tid = threadIdx.x, g = tid >> 6, ln = tid & 63;
    const int nl = ln & 15, q = ln >> 4;
    const int el = g * 16 + (ln >> 2);   // gather: edge-local for this lane's quad
    const int p  = ln & 3;               // gather: 16B-quad within row
    const int G  = gridDim.x;

    // register B-frags: this wave's n-quarter (cols g*32..+31), K=128
    bf16x8 bfrag[8];
    #pragma unroll
    for (int kk = 0; kk < 4; ++kk)
        #pragma unroll
        for (int nt = 0; nt < 2; ++nt)
            bfrag[kk * 2 + nt] =
                *(const bf16x8*)(W2F + (((kk * 8 + g * 2 + nt) * 64 + ln) << 3));
    float b2c[2], w3c[2];
    #pragma unroll
    for (int nt = 0; nt < 2; ++nt) {
        int n = g * 32 + nt * 16 + nl;
        b2c[nt] = b2[n]; w3c[nt] = W3[n];
    }
    const float b3c = b3[0];

    uint4 ga[4], gb[4];
    int uB = 0, vB = 0;                  // indices for tile t+G (gathered next iter)
    int t = blockIdx.x;
    if (t < ntiles) {
        // prologue: indices + gather for tile t (per-lane direct, quad-broadcast)
        int e0 = t * 64 + el;
        int u0 = 0, v0 = 0;
        if (e0 < E) { u0 = src[e0]; v0 = dst[e0]; }
        const uint32_t* ap = Am + (size_t)u0 * 64 + p * 4;
        const uint32_t* bp = Bm + (size_t)v0 * 64 + p * 4;
        #pragma unroll
        for (int r = 0; r < 4; ++r) {
            ga[r] = *(const uint4*)(ap + r * 16);
            gb[r] = *(const uint4*)(bp + r * 16);
        }
        int t1 = t + G;                  // prologue idx-prefetch for t+G
        if (t1 < ntiles) {
            int e1 = t1 * 64 + el;
            if (e1 < E) { uB = src[e1]; vB = dst[e1]; }
        }
    }
    int buf = 0, prev = -1;
    for (; t < ntiles; t += G) {
        // ---- commit gather: sigmoid + pack -> hlds ----
        #pragma unroll
        for (int r = 0; r < 4; ++r) {
            uint32_t sa[4] = {ga[r].x, ga[r].y, ga[r].z, ga[r].w};
            uint32_t sb[4] = {gb[r].x, gb[r].y, gb[r].z, gb[r].w};
            uint32_t da[4];
            #pragma unroll
            for (int d = 0; d < 4; ++d) {
                float zl = bf2f_lo(sa[d]) + bf2f_lo(sb[d]);
                float zh = bf2f_hi(sa[d]) + bf2f_hi(sb[d]);
                da[d] = packbf_rhu(sigmoid_fast(zl), sigmoid_fast(zh));
            }
            *(uint4*)&hlds[el * 136 + r * 32 + p * 8] =
                make_uint4(da[0], da[1], da[2], da[3]);
        }
        // ---- issue idx loads for t+2G (consumed two iterations from now) ----
        int uC = 0, vC = 0;
        int t2 = t + 2 * G;
        if (t2 < ntiles) {
            int e2 = t2 * 64 + el;
            if (e2 < E) { uC = src[e2]; vC = dst[e2]; }
        }
        // ---- issue gathers for t+G (indices resident since last iteration) ----
        if (t + G < ntiles) {
            const uint32_t* ap = Am + (size_t)uB * 64 + p * 4;
            const uint32_t* bp = Bm + (size_t)vB * 64 + p * 4;
            #pragma unroll
            for (int r = 0; r < 4; ++r) {
                ga[r] = *(const uint4*)(ap + r * 16);
                gb[r] = *(const uint4*)(bp + r * 16);
            }
        }
        __syncthreads();   // bar1: hlds ready; part[buf^1] (prev tile) complete

        // ---- delayed out-write for previous tile ----
        if (prev >= 0 && tid < 64) {
            int e = prev * 64 + tid;
            if (e < E)
                out[e] = (part[buf ^ 1][tid] + part[buf ^ 1][64 + tid])
                       + (part[buf ^ 1][128 + tid] + part[buf ^ 1][192 + tid]) + b3c;
        }

        // ---- MFMA + epilogue -> part[buf] ----
        #pragma unroll
        for (int m = 0; m < 4; ++m) {
            f32x4 acc[2];
            #pragma unroll
            for (int r = 0; r < 4; ++r) { acc[0][r] = 0.f; acc[1][r] = 0.f; }
            const ushort* arow = &hlds[(m * 16 + nl) * 136 + (q << 3)];
            #pragma unroll
            for (int kk = 0; kk < 4; ++kk) {
                bf16x8 a = *(const bf16x8*)(arow + kk * 32);
                acc[0] = __builtin_amdgcn_mfma_f32_16x16x32_bf16(a, bfrag[kk * 2],     acc[0], 0, 0, 0);
                acc[1] = __builtin_amdgcn_mfma_f32_16x16x32_bf16(a, bfrag[kk * 2 + 1], acc[1], 0, 0, 0);
            }
            float pr[4] = {0.f, 0.f, 0.f, 0.f};
            #pragma unroll
            for (int nt = 0; nt < 2; ++nt)
                #pragma unroll
                for (int r = 0; r < 4; ++r)
                    pr[r] = fmaf(w3c[nt], sigmoid_fast(acc[nt][r] + b2c[nt]), pr[r]);
            #pragma unroll
            for (int r = 0; r < 4; ++r) {
                pr[r] += __shfl_xor(pr[r], 1, 16);
                pr[r] += __shfl_xor(pr[r], 2, 16);
                pr[r] += __shfl_xor(pr[r], 4, 16);
                pr[r] += __shfl_xor(pr[r], 8, 16);
            }
            if (nl == 0) {
                #pragma unroll
                for (int r = 0; r < 4; ++r)
                    part[buf][g * 64 + m * 16 + q * 4 + r] = pr[r];
            }
        }
        __syncthreads();   // bar2: hlds consumed; part[buf] complete
        uB = uC; vB = vC;
        prev = t; buf ^= 1;
    }
    // ---- drain: out-write for the final tile (bar2 already synced part) ----
    if (prev >= 0 && tid < 64) {
        int e = prev * 64 + tid;
        if (e < E)
            out[e] = (part[buf ^ 1][tid] + part[buf ^ 1][64 + tid])
                   + (part[buf ^ 1][128 + tid] + part[buf ^ 1][192 + tid]) + b3c;
    }
}

// ---------- fallback (only if workspace too small) ----------
__global__ void naive_kernel(
    const float* __restrict__ h1, const float* __restrict__ h2,
    const int* __restrict__ src, const int* __restrict__ dst,
    const float* __restrict__ W1, const float* __restrict__ b1,
    const float* __restrict__ W2, const float* __restrict__ b2,
    const float* __restrict__ W3, const float* __restrict__ b3,
    float* __restrict__ out, int E, int N)
{
    int e = blockIdx.x * blockDim.x + threadIdx.x;
    if (e >= E) return;
    int u = src[e], v = dst[e];
    float h[128];
    for (int j = 0; j < 128; ++j) {
        float z = b1[j];
        const float* wj = W1 + j * 256;
        for (int k = 0; k < 64; ++k) {
            z += wj[k] * h1[(size_t)u * 64 + k]
               + wj[64 + k] * h1[(size_t)v * 64 + k]
               + (wj[128 + k] + wj[192 + k]) * h2[(size_t)u * 64 + k];
        }
        h[j] = 1.0f / (1.0f + __expf(-z));
    }
    float gg[128];
    for (int j = 0; j < 128; ++j) {
        float z = b2[j];
        for (int k = 0; k < 128; ++k) z = fmaf(W2[j * 128 + k], h[k], z);
        gg[j] = 1.0f / (1.0f + __expf(-z));
    }
    float s = b3[0];
    for (int j = 0; j < 128; ++j) s = fmaf(W3[j], gg[j], s);
    out[e] = s;
}

extern "C" void kernel_launch(void* const* d_in, const int* in_sizes, int n_in,
                              void* d_out, int out_size, void* d_ws, size_t ws_size,
                              hipStream_t stream) {
    const float* h1 = (const float*)d_in[0];
    const float* h2 = (const float*)d_in[1];
    const int*  src = (const int*)d_in[2];
    const int*  dst = (const int*)d_in[3];
    const float* W1 = (const float*)d_in[4];
    const float* b1 = (const float*)d_in[5];
    const float* W2 = (const float*)d_in[6];
    const float* b2 = (const float*)d_in[7];
    const float* W3 = (const float*)d_in[8];
    const float* b3 = (const float*)d_in[9];
    float* out = (float*)d_out;

    const int N = in_sizes[0] / 64;
    const int E = in_sizes[2];

    // workspace layout (float units)
    size_t offA   = 0;                         // N*64 dwords (bf16-pair packed)
    size_t offB   = offA + (size_t)N * 64;
    size_t offWCF = offB + (size_t)N * 64;     // 16384 ushorts
    size_t offWBF = offWCF + 8192;             // 8192 ushorts
    size_t offW2F = offWBF + 4096;             // 16384 ushorts
    size_t totalF = offW2F + 8192;

    if (ws_size < totalF * sizeof(float)) {
        naive_kernel<<<(E + 255) / 256, 256, 0, stream>>>(
            h1, h2, src, dst, W1, b1, W2, b2, W3, b3, out, E, N);
        return;
    }

    float* ws = (float*)d_ws;
    ushort* WCF = (ushort*)(ws + offWCF);
    ushort* WBF = (ushort*)(ws + offWBF);
    ushort* W2F = (ushort*)(ws + offW2F);

    prep_kernel<<<64, 256, 0, stream>>>(W1, W2, WCF, WBF, W2F);
    node_kernel<<<(N + 63) / 64, 256, 0, stream>>>(
        h1, h2, WCF, WBF, b1, (uint32_t*)(ws + offA), (uint32_t*)(ws + offB), N);
    const int ntiles = (E + 63) / 64;
    const int nblk = ntiles < 2048 ? ntiles : 2048;   // 8 blocks/CU resident (19.5KB LDS)
    edge_kernel<<<nblk, 256, 0, stream>>>(
        (const uint32_t*)(ws + offA), (const uint32_t*)(ws + offB), src, dst,
        W2F, b2, W3, b3, out, E, ntiles);
}

// Round 5
// 130.552 us; speedup vs baseline: 1.7323x; 1.0318x over previous
//
#include <hip/hip_runtime.h>
#include <hip/hip_bf16.h>
#include <cstdint>

// EdgeMLP: score = W3 @ sig(W2 @ sig(W1 @ [h1_u,h1_v,h2_u,h2_u] + b1) + b2) + b3
// Factored: z1 = Anode[src] + Bnode[dst]  (A/B stored bf16, PERMUTED col order:
//   dword slot d of a row holds true cols (32*(d>>4) + (d&15), +16) as (lo,hi);
//   compensated in W2F's k-index in prep).
// R12: barrier-free edge kernel. R9/R11 showed 44 µs invariant under grid /
//   occupancy-cap / prefetch changes -> wall is the 2-barrier 4-wave lockstep +
//   cross-wave LDS tile. Now each wave owns 16 edges x ALL 128 cols:
//   gather -> sigmoid commit -> 16x ds_bpermute in-register transpose
//   (target lane (q,nl) pulls da[kk][j] from lane nl*4+q) -> 32 MFMA ->
//   epilogue -> direct float4 out store. Zero __syncthreads, zero LDS arrays.
//   Full W2F register-resident (128 VGPR); ~210 total; __launch_bounds__(256,2).

typedef __attribute__((ext_vector_type(8))) short bf16x8;
typedef __attribute__((ext_vector_type(4))) float f32x4;
typedef __attribute__((ext_vector_type(4))) int   i32x4;

__device__ __forceinline__ float sigmoid_fast(float x) {
    float e = __expf(-x);                       // v_mul + v_exp
    return __builtin_amdgcn_rcpf(1.0f + e);     // v_add + v_rcp  (~1 ulp)
}
__device__ __forceinline__ ushort f2bf_rne(float f) {      // prep path only
    uint32_t u = __float_as_uint(f);
    return (ushort)((u + 0x7fffu + ((u >> 16) & 1u)) >> 16);
}
__device__ __forceinline__ float bf2f_lo(uint32_t d) { return __uint_as_float(d << 16); }
__device__ __forceinline__ float bf2f_hi(uint32_t d) { return __uint_as_float(d & 0xffff0000u); }
__device__ __forceinline__ uint32_t packbf_rhu(float x, float y) {   // round-half-up
    return ((__float_as_uint(x) + 0x8000u) >> 16) |
           ((__float_as_uint(y) + 0x8000u) & 0xffff0000u);
}

// ---------- prep: weights -> bf16 MFMA B-fragment layouts ----------
// frag idx: ((kk*8+nt)*64+lane)*8 + j ; n = nt*16+(lane&15) ; kpos = kk*32+(lane>>4)*8+j
// WCF/WBF use true k = kpos. W2F uses permuted ktrue to match A/B dword packing.
__global__ void prep_kernel(const float* __restrict__ W1, const float* __restrict__ W2,
                            ushort* __restrict__ WCF, ushort* __restrict__ WBF,
                            ushort* __restrict__ W2F) {
    int i = blockIdx.x * blockDim.x + threadIdx.x;
    if (i >= 16384) return;
    int j = i & 7, lf = (i >> 3) & 63, nt = (i >> 9) & 7, kk = i >> 12;
    int n = nt * 16 + (lf & 15);
    int kpos = kk * 32 + ((lf >> 4) << 3) + j;
    int ktrue = (kpos & ~31) | ((kpos >> 1) & 15) | ((kpos & 1) << 4);
    W2F[i] = f2bf_rne(W2[n * 128 + ktrue]);
    float v = (kpos < 64) ? W1[n * 256 + kpos]
                          : W1[n * 256 + 128 + (kpos - 64)] + W1[n * 256 + 192 + (kpos - 64)];
    WCF[i] = f2bf_rne(v);
    if (kk < 2) WBF[i] = f2bf_rne(W1[n * 256 + 64 + kpos]);   // K=64: h1-half only
}

// ---------- node-side: MFMA, register weight frags, direct coalesced stores ----------
__global__ __launch_bounds__(256, 4) void node_kernel(
    const float* __restrict__ h1, const float* __restrict__ h2,
    const ushort* __restrict__ WCF, const ushort* __restrict__ WBF,
    const float* __restrict__ b1,
    uint32_t* __restrict__ Aout, uint32_t* __restrict__ Bout, int N)
{
    __shared__ __align__(16) ushort xt[64 * 136];   // [node][k true order]
    const int tid = threadIdx.x, g = tid >> 6, ln = tid & 63;
    const int nl = ln & 15, q = ln >> 4;
    const int n0 = blockIdx.x * 64;
    const bool full = (n0 + 64 <= N);

    // wave g owns n-cols [g*32, g*32+32): 12 weight frags -> 48 VGPRs
    bf16x8 fa[4][2], fb[2][2];
    #pragma unroll
    for (int kk = 0; kk < 4; ++kk)
        #pragma unroll
        for (int nt = 0; nt < 2; ++nt)
            fa[kk][nt] = *(const bf16x8*)(WCF + (((kk * 8 + g * 2 + nt) * 64 + ln) << 3));
    #pragma unroll
    for (int kk = 0; kk < 2; ++kk)
        #pragma unroll
        for (int nt = 0; nt < 2; ++nt)
            fb[kk][nt] = *(const bf16x8*)(WBF + (((kk * 8 + g * 2 + nt) * 64 + ln) << 3));
    const float b1c0 = b1[g * 32 + nl], b1c1 = b1[g * 32 + 16 + nl];

    // stage X = [h1|h2] as bf16 (true k order)
    #pragma unroll
    for (int i = 0; i < 8; ++i) {
        int local = i * 256 + tid;
        int node = local >> 5;
        int kq = (local & 31) * 4;
        float4 x = make_float4(0.f, 0.f, 0.f, 0.f);
        if (full || n0 + node < N)
            x = (kq < 64) ? *(const float4*)(h1 + (size_t)(n0 + node) * 64 + kq)
                          : *(const float4*)(h2 + (size_t)(n0 + node) * 64 + (kq - 64));
        uint32_t d0 = packbf_rhu(x.x, x.y), d1 = packbf_rhu(x.z, x.w);
        *(uint2*)&xt[node * 136 + kq] = make_uint2(d0, d1);
    }
    __syncthreads();

    #pragma unroll
    for (int m = 0; m < 4; ++m) {
        f32x4 accA[2], accB[2];
        #pragma unroll
        for (int r = 0; r < 4; ++r) { accA[0][r] = accA[1][r] = accB[0][r] = accB[1][r] = 0.f; }
        const ushort* arow = &xt[(m * 16 + nl) * 136 + (q << 3)];
        #pragma unroll
        for (int kk = 0; kk < 4; ++kk) {
            bf16x8 a = *(const bf16x8*)(arow + kk * 32);
            accA[0] = __builtin_amdgcn_mfma_f32_16x16x32_bf16(a, fa[kk][0], accA[0], 0, 0, 0);
            accA[1] = __builtin_amdgcn_mfma_f32_16x16x32_bf16(a, fa[kk][1], accA[1], 0, 0, 0);
            if (kk < 2) {
                accB[0] = __builtin_amdgcn_mfma_f32_16x16x32_bf16(a, fb[kk][0], accB[0], 0, 0, 0);
                accB[1] = __builtin_amdgcn_mfma_f32_16x16x32_bf16(a, fb[kk][1], accB[1], 0, 0, 0);
            }
        }
        // C/D: node = m*16 + q*4 + r, cols (g*32+nl, +16) -> dword slot g*16+nl
        #pragma unroll
        for (int r = 0; r < 4; ++r) {
            int node = n0 + m * 16 + q * 4 + r;
            if (full || node < N) {
                Aout[(size_t)node * 64 + g * 16 + nl] = packbf_rhu(accA[0][r] + b1c0, accA[1][r] + b1c1);
                Bout[(size_t)node * 64 + g * 16 + nl] = packbf_rhu(accB[0][r], accB[1][r]);
            }
        }
    }
}

// ---------- edge-side: barrier-free, per-wave-independent ----------
// Wave handles edges [t*64+g*16, +16) for ALL 128 n-cols.
// Gather layout: lane ln -> edge el=ln>>2, 16B-quad p=ln&3; ga/gb[r] covers
//   dwords d = r*16 + p*4 + j of the edge's 64-dword row.
// A-frag needs: lane (q,nl) <- dwords kk*16+q*4+j of edge nl
//   = source lane nl*4+q, reg da[kk][j]  -> one bpermute addr for all 16.
__global__ __launch_bounds__(256, 2) void edge_kernel(
    const uint32_t* __restrict__ Am, const uint32_t* __restrict__ Bm,
    const int* __restrict__ src, const int* __restrict__ dst,
    const ushort* __restrict__ W2F, const float* __restrict__ b2,
    const float* __restrict__ W3, const float* __restrict__ b3,
    float* __restrict__ out, int E, int ntiles)
{
    const int tid = threadIdx.x, g = tid >> 6, ln = tid & 63;
    const int nl = ln & 15, q = ln >> 4;
    const int el = ln >> 2;              // edge-local 0..15 for this lane's quad
    const int p  = ln & 3;               // 16B-quad within row
    const int G  = gridDim.x;
    const int sl = ((nl << 2) | q) << 2; // bpermute byte-addr: source lane nl*4+q

    // full W2F register-resident: 32 frags = 128 VGPR
    bf16x8 bfrag[4][8];
    #pragma unroll
    for (int kk = 0; kk < 4; ++kk)
        #pragma unroll
        for (int nt = 0; nt < 8; ++nt)
            bfrag[kk][nt] = *(const bf16x8*)(W2F + (((kk * 8 + nt) * 64 + ln) << 3));
    float b2c[8], w3c[8];
    #pragma unroll
    for (int nt = 0; nt < 8; ++nt) {
        int n = nt * 16 + nl;
        b2c[nt] = b2[n]; w3c[nt] = W3[n];
    }
    const float b3c = b3[0];

    uint4 ga[4], gb[4];
    int uB = 0, vB = 0;                  // indices for tile t+G (gathered next iter)
    int t = blockIdx.x;
    if (t < ntiles) {
        int e0 = t * 64 + g * 16 + el;
        int u0 = 0, v0 = 0;
        if (e0 < E) { u0 = src[e0]; v0 = dst[e0]; }
        const uint32_t* ap = Am + (size_t)u0 * 64 + p * 4;
        const uint32_t* bp = Bm + (size_t)v0 * 64 + p * 4;
        #pragma unroll
        for (int r = 0; r < 4; ++r) {
            ga[r] = *(const uint4*)(ap + r * 16);
            gb[r] = *(const uint4*)(bp + r * 16);
        }
        int t1 = t + G;
        if (t1 < ntiles) {
            int e1 = t1 * 64 + g * 16 + el;
            if (e1 < E) { uB = src[e1]; vB = dst[e1]; }
        }
    }
    for (; t < ntiles; t += G) {
        // ---- commit: sigmoid + pack (16 edges of this wave) ----
        i32x4 da[4];
        #pragma unroll
        for (int r = 0; r < 4; ++r) {
            uint32_t sa[4] = {ga[r].x, ga[r].y, ga[r].z, ga[r].w};
            uint32_t sb[4] = {gb[r].x, gb[r].y, gb[r].z, gb[r].w};
            #pragma unroll
            for (int d = 0; d < 4; ++d) {
                float zl = bf2f_lo(sa[d]) + bf2f_lo(sb[d]);
                float zh = bf2f_hi(sa[d]) + bf2f_hi(sb[d]);
                da[r][d] = (int)packbf_rhu(sigmoid_fast(zl), sigmoid_fast(zh));
            }
        }
        // ---- issue idx loads for t+2G ----
        int uC = 0, vC = 0;
        int t2 = t + 2 * G;
        if (t2 < ntiles) {
            int e2 = t2 * 64 + g * 16 + el;
            if (e2 < E) { uC = src[e2]; vC = dst[e2]; }
        }
        // ---- issue gathers for t+G (ga/gb free after commit) ----
        if (t + G < ntiles) {
            const uint32_t* ap = Am + (size_t)uB * 64 + p * 4;
            const uint32_t* bp = Bm + (size_t)vB * 64 + p * 4;
            #pragma unroll
            for (int r = 0; r < 4; ++r) {
                ga[r] = *(const uint4*)(ap + r * 16);
                gb[r] = *(const uint4*)(bp + r * 16);
            }
        }
        // ---- in-register transpose: pa[kk] = A-frag for k-slice kk ----
        i32x4 pa[4];
        #pragma unroll
        for (int kk = 0; kk < 4; ++kk)
            #pragma unroll
            for (int j = 0; j < 4; ++j)
                pa[kk][j] = __builtin_amdgcn_ds_bpermute(sl, da[kk][j]);

        // ---- MFMA per n-tile + fused layer3 epilogue ----
        float pr[4] = {0.f, 0.f, 0.f, 0.f};
        #pragma unroll
        for (int nt = 0; nt < 8; ++nt) {
            f32x4 acc = {0.f, 0.f, 0.f, 0.f};
            #pragma unroll
            for (int kk = 0; kk < 4; ++kk)
                acc = __builtin_amdgcn_mfma_f32_16x16x32_bf16(
                    __builtin_bit_cast(bf16x8, pa[kk]), bfrag[kk][nt], acc, 0, 0, 0);
            #pragma unroll
            for (int r = 0; r < 4; ++r)
                pr[r] = fmaf(w3c[nt], sigmoid_fast(acc[r] + b2c[nt]), pr[r]);
        }
        // reduce over the 16 n-lanes (cols); D-row = edge q*4+r
        #pragma unroll
        for (int r = 0; r < 4; ++r) {
            pr[r] += __shfl_xor(pr[r], 1, 16);
            pr[r] += __shfl_xor(pr[r], 2, 16);
            pr[r] += __shfl_xor(pr[r], 4, 16);
            pr[r] += __shfl_xor(pr[r], 8, 16);
        }
        if (nl == 0) {
            int e0 = t * 64 + g * 16 + q * 4;
            if (e0 + 4 <= E) {
                f32x4 v = {pr[0] + b3c, pr[1] + b3c, pr[2] + b3c, pr[3] + b3c};
                *(f32x4*)(out + e0) = v;
            } else {
                #pragma unroll
                for (int r = 0; r < 4; ++r)
                    if (e0 + r < E) out[e0 + r] = pr[r] + b3c;
            }
        }
        uB = uC; vB = vC;
    }
}

// ---------- fallback (only if workspace too small) ----------
__global__ void naive_kernel(
    const float* __restrict__ h1, const float* __restrict__ h2,
    const int* __restrict__ src, const int* __restrict__ dst,
    const float* __restrict__ W1, const float* __restrict__ b1,
    const float* __restrict__ W2, const float* __restrict__ b2,
    const float* __restrict__ W3, const float* __restrict__ b3,
    float* __restrict__ out, int E, int N)
{
    int e = blockIdx.x * blockDim.x + threadIdx.x;
    if (e >= E) return;
    int u = src[e], v = dst[e];
    float h[128];
    for (int j = 0; j < 128; ++j) {
        float z = b1[j];
        const float* wj = W1 + j * 256;
        for (int k = 0; k < 64; ++k) {
            z += wj[k] * h1[(size_t)u * 64 + k]
               + wj[64 + k] * h1[(size_t)v * 64 + k]
               + (wj[128 + k] + wj[192 + k]) * h2[(size_t)u * 64 + k];
        }
        h[j] = 1.0f / (1.0f + __expf(-z));
    }
    float gg[128];
    for (int j = 0; j < 128; ++j) {
        float z = b2[j];
        for (int k = 0; k < 128; ++k) z = fmaf(W2[j * 128 + k], h[k], z);
        gg[j] = 1.0f / (1.0f + __expf(-z));
    }
    float s = b3[0];
    for (int j = 0; j < 128; ++j) s = fmaf(W3[j], gg[j], s);
    out[e] = s;
}

extern "C" void kernel_launch(void* const* d_in, const int* in_sizes, int n_in,
                              void* d_out, int out_size, void* d_ws, size_t ws_size,
                              hipStream_t stream) {
    const float* h1 = (const float*)d_in[0];
    const float* h2 = (const float*)d_in[1];
    const int*  src = (const int*)d_in[2];
    const int*  dst = (const int*)d_in[3];
    const float* W1 = (const float*)d_in[4];
    const float* b1 = (const float*)d_in[5];
    const float* W2 = (const float*)d_in[6];
    const float* b2 = (const float*)d_in[7];
    const float* W3 = (const float*)d_in[8];
    const float* b3 = (const float*)d_in[9];
    float* out = (float*)d_out;

    const int N = in_sizes[0] / 64;
    const int E = in_sizes[2];

    // workspace layout (float units)
    size_t offA   = 0;                         // N*64 dwords (bf16-pair packed)
    size_t offB   = offA + (size_t)N * 64;
    size_t offWCF = offB + (size_t)N * 64;     // 16384 ushorts
    size_t offWBF = offWCF + 8192;             // 8192 ushorts
    size_t offW2F = offWBF + 4096;             // 16384 ushorts
    size_t totalF = offW2F + 8192;

    if (ws_size < totalF * sizeof(float)) {
        naive_kernel<<<(E + 255) / 256, 256, 0, stream>>>(
            h1, h2, src, dst, W1, b1, W2, b2, W3, b3, out, E, N);
        return;
    }

    float* ws = (float*)d_ws;
    ushort* WCF = (ushort*)(ws + offWCF);
    ushort* WBF = (ushort*)(ws + offWBF);
    ushort* W2F = (ushort*)(ws + offW2F);

    prep_kernel<<<64, 256, 0, stream>>>(W1, W2, WCF, WBF, W2F);
    node_kernel<<<(N + 63) / 64, 256, 0, stream>>>(
        h1, h2, WCF, WBF, b1, (uint32_t*)(ws + offA), (uint32_t*)(ws + offB), N);
    const int ntiles = (E + 63) / 64;
    const int nblk = ntiles < 512 ? ntiles : 512;   // 2 blocks/CU at 2 waves/SIMD
    edge_kernel<<<nblk, 256, 0, stream>>>(
        (const uint32_t*)(ws + offA), (const uint32_t*)(ws + offB), src, dst,
        W2F, b2, W3, b3, out, E, ntiles);
}